// Round 15
// baseline (408.583 us; speedup 1.0000x reference)
//
#include <hip/hip_runtime.h>
#include <hip/hip_bf16.h>

#define N_PAPER 100000
#define N_LABEL 128
#define E_CITES 1600000
#define E_IS    100000
#define NBKT    98     // node>>10 buckets
#define A2_CHUNK 2048
#define LSPLIT  8
#define CAPC    24576  // per-bucket capacity, cites (mean 16384)
#define CAPR    2048   // rev (mean 1024)
#define CAPL    8192   // label (mean 781)
#define NS1     ((size_t)N_PAPER * 16)   // slice stride bytes, layer1 (16 dims fp8)
#define NS2     ((size_t)N_PAPER * 8)    // slice stride bytes, layer2 (8 dims fp8)

typedef __bf16 bf16x8 __attribute__((ext_vector_type(8)));
typedef float  f32x4  __attribute__((ext_vector_type(4)));
typedef float  f32x2  __attribute__((ext_vector_type(2)));

static __device__ __forceinline__ float bf_lo(unsigned u) {
    union { unsigned u; float f; } v; v.u = u << 16; return v.f;
}
static __device__ __forceinline__ float bf_hi(unsigned u) {
    union { unsigned u; float f; } v; v.u = u & 0xffff0000u; return v.f;
}
static __device__ __forceinline__ unsigned pk_bf(float a, float b) {
    __hip_bfloat16 x = __float2bfloat16(a), y = __float2bfloat16(b);
    unsigned short ux = *(unsigned short*)&x, uy = *(unsigned short*)&y;
    return (unsigned)ux | ((unsigned)uy << 16);
}
// fp8 e4m3 (OCP on gfx950) encode/decode via HW cvt
static __device__ __forceinline__ unsigned char enc_fp8(float v) {
    return (unsigned char)(__builtin_amdgcn_cvt_pk_fp8_f32(v, v, 0, false) & 0xFF);
}
static __device__ __forceinline__ void dec4(unsigned u, float* o) {
    f32x2 a = __builtin_amdgcn_cvt_pk_f32_fp8((int)u, false);
    f32x2 b = __builtin_amdgcn_cvt_pk_f32_fp8((int)u, true);
    o[0] = a[0]; o[1] = a[1]; o[2] = b[0]; o[3] = b[1];
}

// ---------------- fused bucketed edge scatter into PADDED buckets -----------
#define NSC ((E_CITES + A2_CHUNK - 1) / A2_CHUNK)
#define NSI ((E_IS + A2_CHUNK - 1) / A2_CHUNK)
__global__ __launch_bounds__(256) void fused_scatter(
    const int* __restrict__ cd, const int* __restrict__ cs,
    const int* __restrict__ iss, const int* __restrict__ isd,
    int* __restrict__ bcur_c, unsigned* __restrict__ ebuf_c,
    int* __restrict__ bcur_r, unsigned* __restrict__ ebuf_r,
    int* __restrict__ bcur_l, unsigned* __restrict__ ebuf_l)
{
    __shared__ int sk[A2_CHUNK], sv[A2_CHUNK];
    __shared__ int h[128], base[128], cur[128];
    int b = blockIdx.x, t = threadIdx.x;
    const int* key; const int* val; int E, shift, b0, cap; int* bcur; unsigned* ebuf;
    if (b < NSC)            { key = cd;  val = cs;  E = E_CITES; bcur = bcur_c; ebuf = ebuf_c; shift = 10; cap = CAPC; b0 = b; }
    else if (b < NSC + NSI) { key = iss; val = isd; E = E_IS;    bcur = bcur_r; ebuf = ebuf_r; shift = 10; cap = CAPR; b0 = b - NSC; }
    else                    { key = isd; val = iss; E = E_IS;    bcur = bcur_l; ebuf = ebuf_l; shift = 0;  cap = CAPL; b0 = b - NSC - NSI; }
    int e0 = b0 * A2_CHUNK;
    int n = min(A2_CHUNK, E - e0);
    for (int i = t; i < 128; i += 256) h[i] = 0;
    __syncthreads();
    for (int i = t; i < n; i += 256) {
        int k = key[e0 + i], v = val[e0 + i];
        sk[i] = k; sv[i] = v;
        atomicAdd(&h[k >> shift], 1);
    }
    __syncthreads();
    for (int i = t; i < 128; i += 256) { base[i] = atomicAdd(&bcur[i], h[i]); cur[i] = 0; }
    __syncthreads();
    for (int i = t; i < n; i += 256) {
        int bb = sk[i] >> shift;
        int p = base[bb] + atomicAdd(&cur[bb], 1);
        ebuf[(size_t)bb * cap + p] = ((unsigned)(sk[i] & 1023) << 17) | (unsigned)sv[i];
    }
}

// ---------------- fused per-bucket CSR build (cites + rev), int2 rowptrs ----
__global__ __launch_bounds__(1024) void fused_csr(
    const unsigned* __restrict__ ebuf_c, const int* __restrict__ bcnt_c,
    int2* __restrict__ rp2_c, int* __restrict__ col_c, float* __restrict__ dinv,
    const unsigned* __restrict__ ebuf_r, const int* __restrict__ bcnt_r,
    int2* __restrict__ rp2_r, int* __restrict__ col_r)
{
    __shared__ int hist[1024];
    __shared__ int sc[1024];
    int bb = blockIdx.x, t = threadIdx.x;
    const unsigned* ebuf; const int* bcnt; int2* rp2; int* col; float* dv; int b, cap;
    if (bb < NBKT) { ebuf = ebuf_c; bcnt = bcnt_c; rp2 = rp2_c; col = col_c; dv = dinv; b = bb; cap = CAPC; }
    else           { ebuf = ebuf_r; bcnt = bcnt_r; rp2 = rp2_r; col = col_r; dv = nullptr; b = bb - NBKT; cap = CAPR; }
    size_t s = (size_t)b * cap;
    int n = bcnt[b];
    hist[t] = 0;
    __syncthreads();
    for (int i = t; i < n; i += 1024)
        atomicAdd(&hist[ebuf[s + i] >> 17], 1);
    __syncthreads();
    int v = hist[t];
    sc[t] = v;
    __syncthreads();
    for (int off = 1; off < 1024; off <<= 1) {
        int u = (t >= off) ? sc[t - off] : 0;
        __syncthreads();
        sc[t] += u;
        __syncthreads();
    }
    int excl = sc[t] - v;
    int node = b * 1024 + t;
    if (node < N_PAPER) {
        rp2[node] = make_int2((int)(s + excl), (int)(s + excl + v));
        if (dv) dv[node] = rsqrtf((float)v + 1.0f);
    }
    __syncthreads();
    hist[t] = (int)(s + excl);   // reuse as running cursor
    __syncthreads();
    for (int i = t; i < n; i += 1024) {
        unsigned u = ebuf[s + i];
        int p = atomicAdd(&hist[u >> 17], 1);
        col[p] = (int)(u & 0x1FFFFu);
    }
}

// ---------------- fused prep: pack_wp(1,2) + yrev1 small_mm (tiny) ----------
__global__ __launch_bounds__(256) void fused_prep(
    const float* __restrict__ g1, const float* __restrict__ r1, __hip_bfloat16* __restrict__ Wp1,
    const float* __restrict__ g2, const float* __restrict__ r2, __hip_bfloat16* __restrict__ Wp2,
    const float* __restrict__ xl, const float* __restrict__ W1rev, float* __restrict__ yrev1)
{
    int b = blockIdx.x, t = threadIdx.x;
    if (b < 128 + 64) {
        bool big = (b < 128);
        const float* g = big ? g1 : g2;
        const float* r = big ? r1 : r2;
        __hip_bfloat16* Wp = big ? Wp1 : Wp2;
        int DG = big ? 128 : 64;
        int i = (big ? b : (b - 128)) * 256 + t;
        int j    = i & 7;
        int lane = (i >> 3) & 63;
        int ks   = (i >> 9) & 3;
        int nt   = i >> 11;
        int k = ks * 32 + (lane >> 4) * 8 + j;
        int c = nt * 16 + (lane & 15);
        float v = (c < DG) ? g[k * DG + c] : r[k * DG + (c - DG)];
        Wp[i] = __float2bfloat16(v);
        return;
    }
    // yrev1: 64 blocks, 2 labels per block
    __shared__ float xrow[2][128];
    int bb = b - (128 + 64);
    int half = t >> 7, tt = t & 127;
    int l = bb * 2 + half;
    xrow[half][tt] = xl[(size_t)l * 128 + tt];
    __syncthreads();
    float o = 0.f;
    for (int k = 0; k < 128; ++k) o = fmaf(xrow[half][k], W1rev[k * 128 + tt], o);
    yrev1[(size_t)l * 128 + tt] = o;
}

// ---------------- MFMA GEMM (LDS-staged Wp): Hg(slice-major fp8), Hr(bf16) --
template<int DG, bool AF32>
__global__ __launch_bounds__(512) void gemm_mfma(
    const void* __restrict__ Av, const __hip_bfloat16* __restrict__ Wp,
    const float* __restrict__ dinv,
    unsigned char* __restrict__ Hg, __hip_bfloat16* __restrict__ Hr, int M)
{
    constexpr int NT2 = 2 * DG / 16;           // 16 (DG=128) or 8 (DG=64)
    __shared__ __hip_bfloat16 wlds[NT2 * 2048]; // 64KB or 32KB
    int tid = threadIdx.x;
    for (int i = tid; i < NT2 * 256; i += 512)
        *(bf16x8*)(wlds + (size_t)i * 8) = *(const bf16x8*)(Wp + (size_t)i * 8);
    __syncthreads();

    int wv = tid >> 6, lane = tid & 63;
    int m0 = blockIdx.x * 128 + wv * 16;
    int row = m0 + (lane & 15);
    int rowc = min(row, M - 1);
    int kg = lane >> 4;

    bf16x8 a[4];
    if constexpr (AF32) {
        const float* ap = (const float*)Av + (size_t)rowc * 128 + kg * 8;
        #pragma unroll
        for (int ks = 0; ks < 4; ++ks) {
            float4 v0 = *(const float4*)(ap + ks * 32);
            float4 v1 = *(const float4*)(ap + ks * 32 + 4);
            bf16x8 f;
            f[0] = (__bf16)v0.x; f[1] = (__bf16)v0.y; f[2] = (__bf16)v0.z; f[3] = (__bf16)v0.w;
            f[4] = (__bf16)v1.x; f[5] = (__bf16)v1.y; f[6] = (__bf16)v1.z; f[7] = (__bf16)v1.w;
            a[ks] = f;
        }
    } else {
        const __hip_bfloat16* ap = (const __hip_bfloat16*)Av + (size_t)rowc * 128 + kg * 8;
        #pragma unroll
        for (int ks = 0; ks < 4; ++ks)
            a[ks] = *(const bf16x8*)(ap + ks * 32);
    }

    f32x4 acc[NT2] = {};
    #pragma unroll
    for (int ks = 0; ks < 4; ++ks) {
        #pragma unroll
        for (int nt = 0; nt < NT2; ++nt) {
            bf16x8 b = *(const bf16x8*)(wlds + ((size_t)(nt * 4 + ks) * 64 + lane) * 8);
            acc[nt] = __builtin_amdgcn_mfma_f32_16x16x32_bf16(a[ks], b, acc[nt], 0, 0, 0);
        }
    }

    int rbase = m0 + (lane >> 4) * 4;
    int c = lane & 15;
    float ds[4];
    #pragma unroll
    for (int r = 0; r < 4; ++r) {
        int rr = rbase + r;
        ds[r] = (rr < M) ? dinv[rr] : 1.f;
    }
    #pragma unroll
    for (int nt = 0; nt < NT2; ++nt) {
        bool isG = (nt < DG / 16);
        if (isG) {
            #pragma unroll
            for (int r = 0; r < 4; ++r) {
                int rr = rbase + r;
                if (rr < M) {
                    unsigned char q = enc_fp8(acc[nt][r] * ds[r]);
                    if constexpr (DG == 128) {
                        // slice = nt (16 dims), within-slice dim = c
                        Hg[(size_t)nt * NS1 + (size_t)rr * 16 + c] = q;
                    } else {
                        // 8-dim slices: slice = nt*2 + (c>>3), within = c&7
                        Hg[(size_t)(nt * 2 + (c >> 3)) * NS2 + (size_t)rr * 8 + (c & 7)] = q;
                    }
                }
            }
        } else {
            int cc = (nt - DG / 16) * 16 + c;
            #pragma unroll
            for (int r = 0; r < 4; ++r) {
                int rr = rbase + r;
                if (rr < M) Hr[(size_t)rr * DG + cc] = __float2bfloat16(acc[nt][r]);
            }
        }
    }
}

// ---------------- dimension-sliced paper assembly, layer 1 (D=128) ----------
// grid = 8 slices x 6250 node-groups; slice = blockIdx&7 -> XCD-resident table.
// Wave: 4 nodes x 8 edge-slots x 2 lanes (16B slice per edge).
__global__ __launch_bounds__(256) void paper_assemble1(
    const unsigned char* __restrict__ Hg, const __hip_bfloat16* __restrict__ Hr,
    const int2* __restrict__ rp2_c, const int* __restrict__ col_c,
    const float* __restrict__ dinv,
    const int2* __restrict__ rp2_r, const int* __restrict__ col_r,
    const float* __restrict__ yrev,
    const float* __restrict__ gcn_b, const float* __restrict__ rev_relb,
    __hip_bfloat16* __restrict__ out)
{
    int b = blockIdx.x;
    int slice = b & 7;
    int nb = (b >> 3) * 16;
    int wv = threadIdx.x >> 6, lane = threadIdx.x & 63;
    int n = nb + wv * 4 + (lane >> 4);
    int slot = (lane >> 1) & 7;
    int sub = lane & 1;
    const unsigned char* tbl = Hg + (size_t)slice * NS1;

    f32x2 a2[4] = {};
    int2 se = rp2_c[n];
    for (int j = se.x + slot; j < se.y; j += 8) {
        unsigned col = (unsigned)col_c[j];
        uint2 u = *(const uint2*)(tbl + col * 16 + sub * 8);
        a2[0] += __builtin_amdgcn_cvt_pk_f32_fp8((int)u.x, false);
        a2[1] += __builtin_amdgcn_cvt_pk_f32_fp8((int)u.x, true);
        a2[2] += __builtin_amdgcn_cvt_pk_f32_fp8((int)u.y, false);
        a2[3] += __builtin_amdgcn_cvt_pk_f32_fp8((int)u.y, true);
    }
    float acc[8];
    #pragma unroll
    for (int k = 0; k < 8; ++k) acc[k] = a2[k >> 1][k & 1];
    #pragma unroll
    for (int k = 0; k < 8; ++k) {
        acc[k] += __shfl_xor(acc[k], 2);
        acc[k] += __shfl_xor(acc[k], 4);
        acc[k] += __shfl_xor(acc[k], 8);
    }
    if (slot != 0) return;

    unsigned d0 = (unsigned)slice * 16 + (unsigned)sub * 8;
    float di = dinv[n];
    float sg[8], sr[8], res[8];
    uint2 ug = *(const uint2*)(tbl + (unsigned)n * 16 + sub * 8);
    dec4(ug.x, sg); dec4(ug.y, sg + 4);
    uint4 ur = *(const uint4*)(Hr + (size_t)n * 128 + d0);
    sr[0] = bf_lo(ur.x); sr[1] = bf_hi(ur.x); sr[2] = bf_lo(ur.y); sr[3] = bf_hi(ur.y);
    sr[4] = bf_lo(ur.z); sr[5] = bf_hi(ur.z); sr[6] = bf_lo(ur.w); sr[7] = bf_hi(ur.w);
    #pragma unroll
    for (int k = 0; k < 8; ++k)
        res[k] = di * (acc[k] + sg[k]) + sr[k] + gcn_b[d0 + k] + rev_relb[d0 + k];

    int2 se2 = rp2_r[n];
    for (int jj = se2.x; jj < se2.y; ++jj) {
        const float* yr = yrev + (size_t)col_r[jj] * 128 + d0;
        #pragma unroll
        for (int k = 0; k < 8; ++k) res[k] += yr[k];
    }
    #pragma unroll
    for (int k = 0; k < 8; ++k) {
        res[k] *= 0.5f;
        res[k] = fmaxf(res[k], 0.f);   // layer-1 ReLU
    }
    uint4 o = make_uint4(pk_bf(res[0], res[1]), pk_bf(res[2], res[3]),
                         pk_bf(res[4], res[5]), pk_bf(res[6], res[7]));
    *(uint4*)(out + (size_t)n * 128 + d0) = o;
}

// ---------------- dimension-sliced paper assembly, layer 2 (D=64) -----------
// grid = 8 slices x 3125 node-groups. Wave: 8 nodes x 8 slots x 1 lane (8B slice).
__global__ __launch_bounds__(256) void paper_assemble2(
    const unsigned char* __restrict__ Hg, const __hip_bfloat16* __restrict__ Hr,
    const int2* __restrict__ rp2_c, const int* __restrict__ col_c,
    const float* __restrict__ dinv,
    const int2* __restrict__ rp2_r, const int* __restrict__ col_r,
    const float* __restrict__ yrev,
    const float* __restrict__ gcn_b, const float* __restrict__ rev_relb,
    float* __restrict__ out)
{
    int b = blockIdx.x;
    int slice = b & 7;
    int nb = (b >> 3) * 32;
    int wv = threadIdx.x >> 6, lane = threadIdx.x & 63;
    int n = nb + wv * 8 + (lane >> 3);
    int slot = lane & 7;
    const unsigned char* tbl = Hg + (size_t)slice * NS2;

    f32x2 a2[4] = {};
    int2 se = rp2_c[n];
    for (int j = se.x + slot; j < se.y; j += 8) {
        unsigned col = (unsigned)col_c[j];
        uint2 u = *(const uint2*)(tbl + col * 8);
        a2[0] += __builtin_amdgcn_cvt_pk_f32_fp8((int)u.x, false);
        a2[1] += __builtin_amdgcn_cvt_pk_f32_fp8((int)u.x, true);
        a2[2] += __builtin_amdgcn_cvt_pk_f32_fp8((int)u.y, false);
        a2[3] += __builtin_amdgcn_cvt_pk_f32_fp8((int)u.y, true);
    }
    float acc[8];
    #pragma unroll
    for (int k = 0; k < 8; ++k) acc[k] = a2[k >> 1][k & 1];
    #pragma unroll
    for (int k = 0; k < 8; ++k) {
        acc[k] += __shfl_xor(acc[k], 1);
        acc[k] += __shfl_xor(acc[k], 2);
        acc[k] += __shfl_xor(acc[k], 4);
    }
    if (slot != 0) return;

    unsigned d0 = (unsigned)slice * 8;
    float di = dinv[n];
    float sg[8], sr[8], res[8];
    uint2 ug = *(const uint2*)(tbl + (unsigned)n * 8);
    dec4(ug.x, sg); dec4(ug.y, sg + 4);
    uint4 ur = *(const uint4*)(Hr + (size_t)n * 64 + d0);
    sr[0] = bf_lo(ur.x); sr[1] = bf_hi(ur.x); sr[2] = bf_lo(ur.y); sr[3] = bf_hi(ur.y);
    sr[4] = bf_lo(ur.z); sr[5] = bf_hi(ur.z); sr[6] = bf_lo(ur.w); sr[7] = bf_hi(ur.w);
    #pragma unroll
    for (int k = 0; k < 8; ++k)
        res[k] = di * (acc[k] + sg[k]) + sr[k] + gcn_b[d0 + k] + rev_relb[d0 + k];

    int2 se2 = rp2_r[n];
    for (int jj = se2.x; jj < se2.y; ++jj) {
        const float* yr = yrev + (size_t)col_r[jj] * 64 + d0;
        #pragma unroll
        for (int k = 0; k < 8; ++k) res[k] += yr[k];
    }
    #pragma unroll
    for (int k = 0; k < 8; ++k) res[k] *= 0.5f;   // no ReLU on final layer
    *(float4*)(out + (size_t)n * 64 + d0) =
        make_float4(res[0], res[1], res[2], res[3]);
    *(float4*)(out + (size_t)n * 64 + d0 + 4) =
        make_float4(res[4], res[5], res[6], res[7]);
}

// ---------------- label-side aggregation (grid: 128 labels x LSPLIT) --------
template<bool AF32>
__global__ __launch_bounds__(128) void label_agg(
    const void* __restrict__ Xv,
    const int* __restrict__ cnt_l, const unsigned* __restrict__ ebuf_l,
    float* __restrict__ partialL)
{
    int l = blockIdx.x, sp = blockIdx.y, t = threadIdx.x;
    int n = cnt_l[l];
    size_t s = (size_t)l * CAPL;
    int per = (n + LSPLIT - 1) / LSPLIT;
    int b = sp * per;
    int en = min(b + per, n);
    float acc = 0.f;
    for (int m = b; m < en; ++m) {
        size_t idx = (size_t)(ebuf_l[s + m] & 0x1FFFFu) * 128 + t;
        if constexpr (AF32) acc += ((const float*)Xv)[idx];
        else                acc += __bfloat162float(((const __hip_bfloat16*)Xv)[idx]);
    }
    partialL[((size_t)l * LSPLIT + sp) * 128 + t] = acc;
}

// ---------------- label-side finish: sum partials + tiny GEMM (+ yrev2) -----
template<int DOUT, bool RELU, bool YREV2>
__global__ __launch_bounds__(128) void label_finish(
    const float* __restrict__ partialL, const float* __restrict__ Xdst,
    const float* __restrict__ relW, const float* __restrict__ rootW,
    const float* __restrict__ relb, float* __restrict__ out,
    const float* __restrict__ W2rev, float* __restrict__ yrev2)
{
    __shared__ float arow[128];
    __shared__ float xrow[128];
    __shared__ float hrow[128];
    int l = blockIdx.x, t = threadIdx.x;
    float a = 0.f;
    #pragma unroll
    for (int sp = 0; sp < LSPLIT; ++sp)
        a += partialL[((size_t)l * LSPLIT + sp) * 128 + t];
    arow[t] = a;
    xrow[t] = Xdst[(size_t)l * 128 + t];
    __syncthreads();
    float o = 0.f;
    if (t < DOUT) {
        o = relb[t];
        for (int k = 0; k < 128; ++k)
            o = fmaf(arow[k], relW[k * DOUT + t], fmaf(xrow[k], rootW[k * DOUT + t], o));
        if (RELU) o = fmaxf(o, 0.f);
        out[(size_t)l * DOUT + t] = o;
    }
    if constexpr (YREV2) {
        hrow[t] = o;           // DOUT == 128 here
        __syncthreads();
        if (t < 64) {
            float y = 0.f;
            for (int k = 0; k < 128; ++k)
                y = fmaf(hrow[k], W2rev[k * 64 + t], y);
            yrev2[(size_t)l * 64 + t] = y;
        }
    }
}

extern "C" void kernel_launch(void* const* d_in, const int* in_sizes, int n_in,
                              void* d_out, int out_size, void* d_ws, size_t ws_size,
                              hipStream_t stream)
{
    const float* xp          = (const float*)d_in[0];
    const float* xl          = (const float*)d_in[1];
    const int*   cs          = (const int*)d_in[2];
    const int*   cd          = (const int*)d_in[3];
    const int*   iss         = (const int*)d_in[4];
    const int*   isd         = (const int*)d_in[5];
    const float* l1_gcn_W    = (const float*)d_in[6];
    const float* l1_gcn_b    = (const float*)d_in[7];
    const float* l1_is_relW  = (const float*)d_in[8];
    const float* l1_is_relb  = (const float*)d_in[9];
    const float* l1_is_rootW = (const float*)d_in[10];
    const float* l1_rev_relW = (const float*)d_in[11];
    const float* l1_rev_relb = (const float*)d_in[12];
    const float* l1_rev_rootW= (const float*)d_in[13];
    const float* l2_gcn_W    = (const float*)d_in[14];
    const float* l2_gcn_b    = (const float*)d_in[15];
    const float* l2_is_relW  = (const float*)d_in[16];
    const float* l2_is_relb  = (const float*)d_in[17];
    const float* l2_is_rootW = (const float*)d_in[18];
    const float* l2_rev_relW = (const float*)d_in[19];
    const float* l2_rev_relb = (const float*)d_in[20];
    const float* l2_rev_rootW= (const float*)d_in[21];

    char* ws = (char*)d_ws;
    size_t off = 0;
    auto alloc = [&](size_t bytes) {
        char* p = ws + off;
        off += (bytes + 255) & ~(size_t)255;
        return p;
    };
    __hip_bfloat16* hp1   = (__hip_bfloat16*)alloc((size_t)N_PAPER * 128 * 2);
    unsigned char*  Hg    = (unsigned char*)alloc((size_t)N_PAPER * 128);
    __hip_bfloat16* Hr    = (__hip_bfloat16*)alloc((size_t)N_PAPER * 128 * 2);
    unsigned* ebuf_c = (unsigned*)alloc((size_t)NBKT * CAPC * 4);
    int*      col_c  = (int*)alloc((size_t)NBKT * CAPC * 4);
    unsigned* ebuf_r = (unsigned*)alloc((size_t)NBKT * CAPR * 4);
    int*      col_r  = (int*)alloc((size_t)NBKT * CAPR * 4);
    unsigned* ebuf_l = (unsigned*)alloc((size_t)N_LABEL * CAPL * 4);
    int2*  rp2_c = (int2*)alloc((size_t)N_PAPER * 8);
    int2*  rp2_r = (int2*)alloc((size_t)N_PAPER * 8);
    // contiguous cursor block (one memset): bcur_c(98) bcur_r(98) bcur_l(128)
    int*   bcur_c = (int*)alloc((size_t)(NBKT + NBKT + 128) * 4);
    int*   bcur_r = bcur_c + NBKT;
    int*   bcur_l = bcur_r + NBKT;
    float* dinv  = (float*)alloc((size_t)N_PAPER * 4);
    __hip_bfloat16* Wp1 = (__hip_bfloat16*)alloc((size_t)32768 * 2);
    __hip_bfloat16* Wp2 = (__hip_bfloat16*)alloc((size_t)16384 * 2);
    float* yrev1 = (float*)alloc(128 * 128 * 4);
    float* yrev2 = (float*)alloc(128 * 64 * 4);
    float* hl1   = (float*)alloc(128 * 128 * 4);
    float* partialL = (float*)alloc((size_t)N_LABEL * LSPLIT * 128 * 4);

    float* zp = (float*)d_out;                          // [100000 x 64]
    float* zl = (float*)d_out + (size_t)N_PAPER * 64;   // [128 x 64]

    hipMemsetAsync(bcur_c, 0, (size_t)(NBKT + NBKT + 128) * 4, stream);

    // ---- CSR builds: single-pass padded-bucket scatter, then per-bucket sort
    fused_scatter<<<NSC + 2 * NSI, 256, 0, stream>>>(cd, cs, iss, isd,
                                                     bcur_c, ebuf_c, bcur_r, ebuf_r, bcur_l, ebuf_l);
    fused_csr<<<2 * NBKT, 1024, 0, stream>>>(ebuf_c, bcur_c, rp2_c, col_c, dinv,
                                             ebuf_r, bcur_r, rp2_r, col_r);
    fused_prep<<<128 + 64 + 64, 256, 0, stream>>>(
        l1_gcn_W, l1_rev_rootW, Wp1, l2_gcn_W, l2_rev_rootW, Wp2,
        xl, l1_rev_relW, yrev1);

    // ---- layer 1 (A = xp fp32 directly) ----
    gemm_mfma<128, true><<<(N_PAPER + 127) / 128, 512, 0, stream>>>(xp, Wp1, dinv, Hg, Hr, N_PAPER);
    paper_assemble1<<<8 * (N_PAPER / 16), 256, 0, stream>>>(
        Hg, Hr, rp2_c, col_c, dinv, rp2_r, col_r, yrev1, l1_gcn_b, l1_rev_relb, hp1);
    label_agg<true><<<dim3(N_LABEL, LSPLIT), 128, 0, stream>>>(xp, bcur_l, ebuf_l, partialL);
    label_finish<128, true, true><<<N_LABEL, 128, 0, stream>>>(
        partialL, xl, l1_is_relW, l1_is_rootW, l1_is_relb, hl1, l2_rev_relW, yrev2);

    // ---- layer 2 ----
    gemm_mfma<64, false><<<(N_PAPER + 127) / 128, 512, 0, stream>>>(hp1, Wp2, dinv, Hg, Hr, N_PAPER);
    paper_assemble2<<<8 * (N_PAPER / 32), 256, 0, stream>>>(
        Hg, Hr, rp2_c, col_c, dinv, rp2_r, col_r, yrev2, l2_gcn_b, l2_rev_relb, zp);
    label_agg<false><<<dim3(N_LABEL, LSPLIT), 128, 0, stream>>>(hp1, bcur_l, ebuf_l, partialL);
    label_finish<64, false, false><<<N_LABEL, 128, 0, stream>>>(
        partialL, hl1, l2_is_relW, l2_is_rootW, l2_is_relb, zl, nullptr, nullptr);
}

// Round 16
// 275.053 us; speedup vs baseline: 1.4855x; 1.4855x over previous
//
#include <hip/hip_runtime.h>
#include <hip/hip_bf16.h>

#define N_PAPER 100000
#define N_LABEL 128
#define E_CITES 1600000
#define E_IS    100000
#define NBKT    98     // node>>10 buckets
#define A2_CHUNK 2048
#define LSPLIT  16
#define CAPC    24576  // per-bucket capacity, cites (mean 16384)
#define CAPR    2048   // rev (mean 1024)
#define CAPL    8192   // label (mean 781)

typedef __bf16 bf16x8 __attribute__((ext_vector_type(8)));
typedef float  f32x4  __attribute__((ext_vector_type(4)));
typedef float  f32x2  __attribute__((ext_vector_type(2)));

static __device__ __forceinline__ float bf_lo(unsigned u) {
    union { unsigned u; float f; } v; v.u = u << 16; return v.f;
}
static __device__ __forceinline__ float bf_hi(unsigned u) {
    union { unsigned u; float f; } v; v.u = u & 0xffff0000u; return v.f;
}
static __device__ __forceinline__ unsigned pk_bf(float a, float b) {
    __hip_bfloat16 x = __float2bfloat16(a), y = __float2bfloat16(b);
    unsigned short ux = *(unsigned short*)&x, uy = *(unsigned short*)&y;
    return (unsigned)ux | ((unsigned)uy << 16);
}
// fp8 e4m3 (OCP on gfx950) encode/decode via HW cvt
static __device__ __forceinline__ unsigned char enc_fp8(float v) {
    return (unsigned char)(__builtin_amdgcn_cvt_pk_fp8_f32(v, v, 0, false) & 0xFF);
}
static __device__ __forceinline__ void dec4(unsigned u, float* o) {
    f32x2 a = __builtin_amdgcn_cvt_pk_f32_fp8((int)u, false);
    f32x2 b = __builtin_amdgcn_cvt_pk_f32_fp8((int)u, true);
    o[0] = a[0]; o[1] = a[1]; o[2] = b[0]; o[3] = b[1];
}

// ---------------- fused scatter (padded buckets) + weight prep --------------
#define NSC ((E_CITES + A2_CHUNK - 1) / A2_CHUNK)
#define NSI ((E_IS + A2_CHUNK - 1) / A2_CHUNK)
#define PREPB (128 + 64 + 64)
__global__ __launch_bounds__(256) void fused_scatter(
    const int* __restrict__ cd, const int* __restrict__ cs,
    const int* __restrict__ iss, const int* __restrict__ isd,
    int* __restrict__ bcur_c, unsigned* __restrict__ ebuf_c,
    int* __restrict__ bcur_r, unsigned* __restrict__ ebuf_r,
    int* __restrict__ bcur_l, unsigned* __restrict__ ebuf_l,
    const float* __restrict__ g1, const float* __restrict__ r1, __hip_bfloat16* __restrict__ Wp1,
    const float* __restrict__ g2, const float* __restrict__ r2, __hip_bfloat16* __restrict__ Wp2,
    const float* __restrict__ xl, const float* __restrict__ W1rev, float* __restrict__ yrev1)
{
    __shared__ int sk[A2_CHUNK], sv[A2_CHUNK];
    __shared__ int h[128], base[128], cur[128];
    __shared__ float xrow[2][128];
    int b = blockIdx.x, t = threadIdx.x;
    if (b >= NSC + 2 * NSI) {
        // ---- prep branch (tiny, independent) ----
        int bp = b - (NSC + 2 * NSI);
        if (bp < 128 + 64) {
            bool big = (bp < 128);
            const float* g = big ? g1 : g2;
            const float* r = big ? r1 : r2;
            __hip_bfloat16* Wp = big ? Wp1 : Wp2;
            int DG = big ? 128 : 64;
            int i = (big ? bp : (bp - 128)) * 256 + t;
            int j    = i & 7;
            int lane = (i >> 3) & 63;
            int ks   = (i >> 9) & 3;
            int nt   = i >> 11;
            int k = ks * 32 + (lane >> 4) * 8 + j;
            int c = nt * 16 + (lane & 15);
            float v = (c < DG) ? g[k * DG + c] : r[k * DG + (c - DG)];
            Wp[i] = __float2bfloat16(v);
            return;
        }
        // yrev1: 64 blocks, 2 labels per block
        int bb = bp - (128 + 64);
        int half = t >> 7, tt = t & 127;
        int l = bb * 2 + half;
        xrow[half][tt] = xl[(size_t)l * 128 + tt];
        __syncthreads();
        float o = 0.f;
        for (int k = 0; k < 128; ++k) o = fmaf(xrow[half][k], W1rev[k * 128 + tt], o);
        yrev1[(size_t)l * 128 + tt] = o;
        return;
    }
    // ---- scatter branch ----
    const int* key; const int* val; int E, shift, b0, cap; int* bcur; unsigned* ebuf;
    if (b < NSC)            { key = cd;  val = cs;  E = E_CITES; bcur = bcur_c; ebuf = ebuf_c; shift = 10; cap = CAPC; b0 = b; }
    else if (b < NSC + NSI) { key = iss; val = isd; E = E_IS;    bcur = bcur_r; ebuf = ebuf_r; shift = 10; cap = CAPR; b0 = b - NSC; }
    else                    { key = isd; val = iss; E = E_IS;    bcur = bcur_l; ebuf = ebuf_l; shift = 0;  cap = CAPL; b0 = b - NSC - NSI; }
    int e0 = b0 * A2_CHUNK;
    int n = min(A2_CHUNK, E - e0);
    for (int i = t; i < 128; i += 256) h[i] = 0;
    __syncthreads();
    for (int i = t; i < n; i += 256) {
        int k = key[e0 + i], v = val[e0 + i];
        sk[i] = k; sv[i] = v;
        atomicAdd(&h[k >> shift], 1);
    }
    __syncthreads();
    for (int i = t; i < 128; i += 256) { base[i] = atomicAdd(&bcur[i], h[i]); cur[i] = 0; }
    __syncthreads();
    for (int i = t; i < n; i += 256) {
        int bb = sk[i] >> shift;
        int p = base[bb] + atomicAdd(&cur[bb], 1);
        ebuf[(size_t)bb * cap + p] = ((unsigned)(sk[i] & 1023) << 17) | (unsigned)sv[i];
    }
}

// ---------------- fused per-bucket CSR build (cites + rev), int2 rowptrs ----
__global__ __launch_bounds__(1024) void fused_csr(
    const unsigned* __restrict__ ebuf_c, const int* __restrict__ bcnt_c,
    int2* __restrict__ rp2_c, int* __restrict__ col_c, float* __restrict__ dinv,
    const unsigned* __restrict__ ebuf_r, const int* __restrict__ bcnt_r,
    int2* __restrict__ rp2_r, int* __restrict__ col_r)
{
    __shared__ int hist[1024];
    __shared__ int sc[1024];
    int bb = blockIdx.x, t = threadIdx.x;
    const unsigned* ebuf; const int* bcnt; int2* rp2; int* col; float* dv; int b, cap;
    if (bb < NBKT) { ebuf = ebuf_c; bcnt = bcnt_c; rp2 = rp2_c; col = col_c; dv = dinv; b = bb; cap = CAPC; }
    else           { ebuf = ebuf_r; bcnt = bcnt_r; rp2 = rp2_r; col = col_r; dv = nullptr; b = bb - NBKT; cap = CAPR; }
    size_t s = (size_t)b * cap;
    int n = bcnt[b];
    hist[t] = 0;
    __syncthreads();
    for (int i = t; i < n; i += 1024)
        atomicAdd(&hist[ebuf[s + i] >> 17], 1);
    __syncthreads();
    int v = hist[t];
    sc[t] = v;
    __syncthreads();
    for (int off = 1; off < 1024; off <<= 1) {
        int u = (t >= off) ? sc[t - off] : 0;
        __syncthreads();
        sc[t] += u;
        __syncthreads();
    }
    int excl = sc[t] - v;
    int node = b * 1024 + t;
    if (node < N_PAPER) {
        rp2[node] = make_int2((int)(s + excl), (int)(s + excl + v));
        if (dv) dv[node] = rsqrtf((float)v + 1.0f);
    }
    __syncthreads();
    hist[t] = (int)(s + excl);   // reuse as running cursor
    __syncthreads();
    for (int i = t; i < n; i += 1024) {
        unsigned u = ebuf[s + i];
        int p = atomicAdd(&hist[u >> 17], 1);
        col[p] = (int)(u & 0x1FFFFu);
    }
}

// ---------------- MFMA GEMM (LDS-staged Wp): Hg = fp8(dinv.*(A@Wg)), Hr = bf16(A@Wr)
template<int DG, bool AF32>
__global__ __launch_bounds__(512) void gemm_mfma(
    const void* __restrict__ Av, const __hip_bfloat16* __restrict__ Wp,
    const float* __restrict__ dinv,
    unsigned char* __restrict__ Hg, __hip_bfloat16* __restrict__ Hr, int M)
{
    constexpr int NT2 = 2 * DG / 16;           // 16 (DG=128) or 8 (DG=64)
    __shared__ __hip_bfloat16 wlds[NT2 * 2048]; // 64KB or 32KB
    int tid = threadIdx.x;
    for (int i = tid; i < NT2 * 256; i += 512)
        *(bf16x8*)(wlds + (size_t)i * 8) = *(const bf16x8*)(Wp + (size_t)i * 8);
    __syncthreads();

    int wv = tid >> 6, lane = tid & 63;
    int m0 = blockIdx.x * 128 + wv * 16;
    int row = m0 + (lane & 15);
    int rowc = min(row, M - 1);
    int kg = lane >> 4;

    bf16x8 a[4];
    if constexpr (AF32) {
        const float* ap = (const float*)Av + (size_t)rowc * 128 + kg * 8;
        #pragma unroll
        for (int ks = 0; ks < 4; ++ks) {
            float4 v0 = *(const float4*)(ap + ks * 32);
            float4 v1 = *(const float4*)(ap + ks * 32 + 4);
            bf16x8 f;
            f[0] = (__bf16)v0.x; f[1] = (__bf16)v0.y; f[2] = (__bf16)v0.z; f[3] = (__bf16)v0.w;
            f[4] = (__bf16)v1.x; f[5] = (__bf16)v1.y; f[6] = (__bf16)v1.z; f[7] = (__bf16)v1.w;
            a[ks] = f;
        }
    } else {
        const __hip_bfloat16* ap = (const __hip_bfloat16*)Av + (size_t)rowc * 128 + kg * 8;
        #pragma unroll
        for (int ks = 0; ks < 4; ++ks)
            a[ks] = *(const bf16x8*)(ap + ks * 32);
    }

    f32x4 acc[NT2] = {};
    #pragma unroll
    for (int ks = 0; ks < 4; ++ks) {
        #pragma unroll
        for (int nt = 0; nt < NT2; ++nt) {
            bf16x8 b = *(const bf16x8*)(wlds + ((size_t)(nt * 4 + ks) * 64 + lane) * 8);
            acc[nt] = __builtin_amdgcn_mfma_f32_16x16x32_bf16(a[ks], b, acc[nt], 0, 0, 0);
        }
    }

    int rbase = m0 + (lane >> 4) * 4;
    int c = lane & 15;
    float ds[4];
    #pragma unroll
    for (int r = 0; r < 4; ++r) {
        int rr = rbase + r;
        ds[r] = (rr < M) ? dinv[rr] : 1.f;
    }
    #pragma unroll
    for (int nt = 0; nt < NT2; ++nt) {
        bool isG = (nt < DG / 16);
        if (isG) {
            int cc = nt * 16 + c;
            #pragma unroll
            for (int r = 0; r < 4; ++r) {
                int rr = rbase + r;
                if (rr < M) Hg[(size_t)rr * DG + cc] = enc_fp8(acc[nt][r] * ds[r]);
            }
        } else {
            int cc = (nt - DG / 16) * 16 + c;
            #pragma unroll
            for (int r = 0; r < 4; ++r) {
                int rr = rbase + r;
                if (rr < M) Hr[(size_t)rr * DG + cc] = __float2bfloat16(acc[nt][r]);
            }
        }
    }
}

// ---------------- fused paper-side assembly (fp8 Hg pre-scaled, bf16 Hr) ----
// D=128: 4 groups x 16 lanes; D=64: 8 groups x 8 lanes. NB=8 both (uint2 fp8/lane).
template<int D, bool RELU, typename OutT>
__global__ __launch_bounds__(256) void paper_assemble(
    const unsigned char* __restrict__ Hg, const __hip_bfloat16* __restrict__ Hr,
    const int2* __restrict__ rp2_c, const int* __restrict__ col_c,
    const float* __restrict__ dinv,
    const int2* __restrict__ rp2_r, const int* __restrict__ col_r,
    const float* __restrict__ yrev,
    const float* __restrict__ gcn_b, const float* __restrict__ rev_relb,
    OutT* __restrict__ out)
{
    constexpr int GL = (D == 128) ? 16 : 8;   // lanes per group
    constexpr int NGRP = 64 / GL;             // edges in flight per wave
    int w = (int)((blockIdx.x * 256 + threadIdx.x) >> 6);
    if (w >= N_PAPER) return;
    int lane = threadIdx.x & 63;
    int grp = lane / GL, sub = lane % GL;
    unsigned d0 = (unsigned)sub * 8;
    f32x2 a2[4] = {};
    int2 se = rp2_c[w];
    int e = se.y;
    int j = se.x + grp;
    for (; j + NGRP < e; j += 2 * NGRP) {
        unsigned o0 = (unsigned)col_c[j] * D + d0;
        unsigned o1 = (unsigned)col_c[j + NGRP] * D + d0;
        uint2 u = *(const uint2*)(Hg + o0);
        uint2 v = *(const uint2*)(Hg + o1);
        a2[0] += __builtin_amdgcn_cvt_pk_f32_fp8((int)u.x, false);
        a2[1] += __builtin_amdgcn_cvt_pk_f32_fp8((int)u.x, true);
        a2[2] += __builtin_amdgcn_cvt_pk_f32_fp8((int)u.y, false);
        a2[3] += __builtin_amdgcn_cvt_pk_f32_fp8((int)u.y, true);
        a2[0] += __builtin_amdgcn_cvt_pk_f32_fp8((int)v.x, false);
        a2[1] += __builtin_amdgcn_cvt_pk_f32_fp8((int)v.x, true);
        a2[2] += __builtin_amdgcn_cvt_pk_f32_fp8((int)v.y, false);
        a2[3] += __builtin_amdgcn_cvt_pk_f32_fp8((int)v.y, true);
    }
    if (j < e) {
        unsigned o0 = (unsigned)col_c[j] * D + d0;
        uint2 u = *(const uint2*)(Hg + o0);
        a2[0] += __builtin_amdgcn_cvt_pk_f32_fp8((int)u.x, false);
        a2[1] += __builtin_amdgcn_cvt_pk_f32_fp8((int)u.x, true);
        a2[2] += __builtin_amdgcn_cvt_pk_f32_fp8((int)u.y, false);
        a2[3] += __builtin_amdgcn_cvt_pk_f32_fp8((int)u.y, true);
    }
    float acc[8];
    #pragma unroll
    for (int k = 0; k < 8; ++k) acc[k] = a2[k >> 1][k & 1];
    #pragma unroll
    for (int k = 0; k < 8; ++k) {
        #pragma unroll
        for (int off = GL; off < 64; off <<= 1)
            acc[k] += __shfl_xor(acc[k], off);
    }
    if (grp != 0) return;

    float di = dinv[w];
    float res[8], sg[8], sr[8];
    const unsigned char* hg = Hg + ((unsigned)w * D + d0);
    const __hip_bfloat16* hr = Hr + (size_t)w * D + d0;
    uint2 ug = *(const uint2*)hg;
    dec4(ug.x, sg); dec4(ug.y, sg + 4);
    uint4 ur = *(const uint4*)hr;
    sr[0] = bf_lo(ur.x); sr[1] = bf_hi(ur.x); sr[2] = bf_lo(ur.y); sr[3] = bf_hi(ur.y);
    sr[4] = bf_lo(ur.z); sr[5] = bf_hi(ur.z); sr[6] = bf_lo(ur.w); sr[7] = bf_hi(ur.w);
    #pragma unroll
    for (int k = 0; k < 8; ++k)
        res[k] = di * (acc[k] + sg[k]) + sr[k] + gcn_b[d0 + k] + rev_relb[d0 + k];

    int2 se2 = rp2_r[w];
    for (int jj = se2.x; jj < se2.y; ++jj) {
        const float* yr = yrev + (size_t)col_r[jj] * D + d0;
        #pragma unroll
        for (int k = 0; k < 8; ++k) res[k] += yr[k];
    }
    #pragma unroll
    for (int k = 0; k < 8; ++k) {
        res[k] *= 0.5f;
        if (RELU) res[k] = fmaxf(res[k], 0.f);
    }
    if constexpr (sizeof(OutT) == 2) {
        uint4 o = make_uint4(pk_bf(res[0], res[1]), pk_bf(res[2], res[3]),
                             pk_bf(res[4], res[5]), pk_bf(res[6], res[7]));
        *(uint4*)(out + (size_t)w * D + d0) = o;
    } else {
        *(float4*)((float*)out + (size_t)w * D + d0) =
            make_float4(res[0], res[1], res[2], res[3]);
        *(float4*)((float*)out + (size_t)w * D + d0 + 4) =
            make_float4(res[4], res[5], res[6], res[7]);
    }
}

// ---------------- label-side aggregation (grid: 128 labels x LSPLIT) --------
template<bool AF32>
__global__ __launch_bounds__(128) void label_agg(
    const void* __restrict__ Xv,
    const int* __restrict__ cnt_l, const unsigned* __restrict__ ebuf_l,
    float* __restrict__ partialL)
{
    int l = blockIdx.x, sp = blockIdx.y, t = threadIdx.x;
    int n = cnt_l[l];
    size_t s = (size_t)l * CAPL;
    int per = (n + LSPLIT - 1) / LSPLIT;
    int b = sp * per;
    int en = min(b + per, n);
    float acc = 0.f;
    for (int m = b; m < en; ++m) {
        size_t idx = (size_t)(ebuf_l[s + m] & 0x1FFFFu) * 128 + t;
        if constexpr (AF32) acc += ((const float*)Xv)[idx];
        else                acc += __bfloat162float(((const __hip_bfloat16*)Xv)[idx]);
    }
    partialL[((size_t)l * LSPLIT + sp) * 128 + t] = acc;
}

// ---------------- label-side finish: sum partials + tiny GEMM (+ yrev2) -----
template<int DOUT, bool RELU, bool YREV2>
__global__ __launch_bounds__(128) void label_finish(
    const float* __restrict__ partialL, const float* __restrict__ Xdst,
    const float* __restrict__ relW, const float* __restrict__ rootW,
    const float* __restrict__ relb, float* __restrict__ out,
    const float* __restrict__ W2rev, float* __restrict__ yrev2)
{
    __shared__ float arow[128];
    __shared__ float xrow[128];
    __shared__ float hrow[128];
    int l = blockIdx.x, t = threadIdx.x;
    float a = 0.f;
    #pragma unroll
    for (int sp = 0; sp < LSPLIT; ++sp)
        a += partialL[((size_t)l * LSPLIT + sp) * 128 + t];
    arow[t] = a;
    xrow[t] = Xdst[(size_t)l * 128 + t];
    __syncthreads();
    float o = 0.f;
    if (t < DOUT) {
        o = relb[t];
        for (int k = 0; k < 128; ++k)
            o = fmaf(arow[k], relW[k * DOUT + t], fmaf(xrow[k], rootW[k * DOUT + t], o));
        if (RELU) o = fmaxf(o, 0.f);
        out[(size_t)l * DOUT + t] = o;
    }
    if constexpr (YREV2) {
        hrow[t] = o;           // DOUT == 128 here
        __syncthreads();
        if (t < 64) {
            float y = 0.f;
            for (int k = 0; k < 128; ++k)
                y = fmaf(hrow[k], W2rev[k * 64 + t], y);
            yrev2[(size_t)l * 64 + t] = y;
        }
    }
}

extern "C" void kernel_launch(void* const* d_in, const int* in_sizes, int n_in,
                              void* d_out, int out_size, void* d_ws, size_t ws_size,
                              hipStream_t stream)
{
    const float* xp          = (const float*)d_in[0];
    const float* xl          = (const float*)d_in[1];
    const int*   cs          = (const int*)d_in[2];
    const int*   cd          = (const int*)d_in[3];
    const int*   iss         = (const int*)d_in[4];
    const int*   isd         = (const int*)d_in[5];
    const float* l1_gcn_W    = (const float*)d_in[6];
    const float* l1_gcn_b    = (const float*)d_in[7];
    const float* l1_is_relW  = (const float*)d_in[8];
    const float* l1_is_relb  = (const float*)d_in[9];
    const float* l1_is_rootW = (const float*)d_in[10];
    const float* l1_rev_relW = (const float*)d_in[11];
    const float* l1_rev_relb = (const float*)d_in[12];
    const float* l1_rev_rootW= (const float*)d_in[13];
    const float* l2_gcn_W    = (const float*)d_in[14];
    const float* l2_gcn_b    = (const float*)d_in[15];
    const float* l2_is_relW  = (const float*)d_in[16];
    const float* l2_is_relb  = (const float*)d_in[17];
    const float* l2_is_rootW = (const float*)d_in[18];
    const float* l2_rev_relW = (const float*)d_in[19];
    const float* l2_rev_relb = (const float*)d_in[20];
    const float* l2_rev_rootW= (const float*)d_in[21];

    char* ws = (char*)d_ws;
    size_t off = 0;
    auto alloc = [&](size_t bytes) {
        char* p = ws + off;
        off += (bytes + 255) & ~(size_t)255;
        return p;
    };
    __hip_bfloat16* hp1   = (__hip_bfloat16*)alloc((size_t)N_PAPER * 128 * 2);
    unsigned char*  Hg    = (unsigned char*)alloc((size_t)N_PAPER * 128);
    __hip_bfloat16* Hr    = (__hip_bfloat16*)alloc((size_t)N_PAPER * 128 * 2);
    unsigned* ebuf_c = (unsigned*)alloc((size_t)NBKT * CAPC * 4);
    int*      col_c  = (int*)alloc((size_t)NBKT * CAPC * 4);
    unsigned* ebuf_r = (unsigned*)alloc((size_t)NBKT * CAPR * 4);
    int*      col_r  = (int*)alloc((size_t)NBKT * CAPR * 4);
    unsigned* ebuf_l = (unsigned*)alloc((size_t)N_LABEL * CAPL * 4);
    int2*  rp2_c = (int2*)alloc((size_t)N_PAPER * 8);
    int2*  rp2_r = (int2*)alloc((size_t)N_PAPER * 8);
    // contiguous cursor block (one memset): bcur_c(98) bcur_r(98) bcur_l(128)
    int*   bcur_c = (int*)alloc((size_t)(NBKT + NBKT + 128) * 4);
    int*   bcur_r = bcur_c + NBKT;
    int*   bcur_l = bcur_r + NBKT;
    float* dinv  = (float*)alloc((size_t)N_PAPER * 4);
    __hip_bfloat16* Wp1 = (__hip_bfloat16*)alloc((size_t)32768 * 2);
    __hip_bfloat16* Wp2 = (__hip_bfloat16*)alloc((size_t)16384 * 2);
    float* yrev1 = (float*)alloc(128 * 128 * 4);
    float* yrev2 = (float*)alloc(128 * 64 * 4);
    float* hl1   = (float*)alloc(128 * 128 * 4);
    float* partialL = (float*)alloc((size_t)N_LABEL * LSPLIT * 128 * 4);

    float* zp = (float*)d_out;                          // [100000 x 64]
    float* zl = (float*)d_out + (size_t)N_PAPER * 64;   // [128 x 64]

    hipMemsetAsync(bcur_c, 0, (size_t)(NBKT + NBKT + 128) * 4, stream);

    // ---- CSR builds + weight prep (one grid); then per-bucket CSR sort ----
    fused_scatter<<<NSC + 2 * NSI + PREPB, 256, 0, stream>>>(
        cd, cs, iss, isd, bcur_c, ebuf_c, bcur_r, ebuf_r, bcur_l, ebuf_l,
        l1_gcn_W, l1_rev_rootW, Wp1, l2_gcn_W, l2_rev_rootW, Wp2,
        xl, l1_rev_relW, yrev1);
    fused_csr<<<2 * NBKT, 1024, 0, stream>>>(ebuf_c, bcur_c, rp2_c, col_c, dinv,
                                             ebuf_r, bcur_r, rp2_r, col_r);

    // ---- layer 1 (A = xp fp32 directly) ----
    gemm_mfma<128, true><<<(N_PAPER + 127) / 128, 512, 0, stream>>>(xp, Wp1, dinv, Hg, Hr, N_PAPER);
    paper_assemble<128, true, __hip_bfloat16><<<(N_PAPER + 3) / 4, 256, 0, stream>>>(
        Hg, Hr, rp2_c, col_c, dinv, rp2_r, col_r, yrev1, l1_gcn_b, l1_rev_relb, hp1);
    label_agg<true><<<dim3(N_LABEL, LSPLIT), 128, 0, stream>>>(xp, bcur_l, ebuf_l, partialL);
    label_finish<128, true, true><<<N_LABEL, 128, 0, stream>>>(
        partialL, xl, l1_is_relW, l1_is_rootW, l1_is_relb, hl1, l2_rev_relW, yrev2);

    // ---- layer 2 ----
    gemm_mfma<64, false><<<(N_PAPER + 127) / 128, 512, 0, stream>>>(hp1, Wp2, dinv, Hg, Hr, N_PAPER);
    paper_assemble<64, false, float><<<(N_PAPER + 3) / 4, 256, 0, stream>>>(
        Hg, Hr, rp2_c, col_c, dinv, rp2_r, col_r, yrev2, l2_gcn_b, l2_rev_relb, zp);
    label_agg<false><<<dim3(N_LABEL, LSPLIT), 128, 0, stream>>>(hp1, bcur_l, ebuf_l, partialL);
    label_finish<64, false, false><<<N_LABEL, 128, 0, stream>>>(
        partialL, hl1, l2_is_relW, l2_is_rootW, l2_is_relb, zl, nullptr, nullptr);
}